// Round 3
// baseline (360.218 us; speedup 1.0000x reference)
//
#include <hip/hip_runtime.h>
#include <float.h>

// PQHead forward: out[b, m*6+d] = codebooks[m, argmax_k dot(x[b,m,:], cb[m,k,:]), d]
// (straight-through estimator: forward value of quant is exactly `discrete`)
//
// R9: select diet on the proven R6 structure.
//  - R8 post-mortem: BROWS=64 destroyed L3 retention (FETCH 52->136 MB,
//    WRITE 110->263 MB). Reverted to BROWS=16 / 4096 blocks.
//  - Invariant across R6/R7/R8: VALU-busy TIME ~46us. The select tree
//    (running top-2 + index, ~64 ops/row) costs 2.7x the dots (24 ops).
//  - New select: pk-max tree + DPP quad-max (7 ops) + epsilon-match mask
//    (d > best1-1e-5, quad-OR'd; ~22 ops). popcount==1 -> ctz is the exact
//    argmax; else -> same quad-uniform fp64 exact fallback as R6 (identical
//    trigger condition: runner-up within 1e-5 of best <=> >=2 mask bits).
//  - launch_bounds 4 -> 6 waves/EU (LDS 24 KiB allows 6 blocks/CU).

typedef float v2f __attribute__((ext_vector_type(2)));

#define BATCH 32768
#define DIM   768
#define K_CB  32
#define D_SUB 6
#define BROWS 16               // rows per block
#define RSTG  8                // rows per LDS stage
#define NSTG  (BROWS/RSTG)     // 2 stages
#define HALFF 384              // floats per half row (64 m * 6)
#define STGF  (RSTG*HALFF)     // 3072 floats = 12 KiB per buffer
#define EPS_TIE 1e-5f

#define DPP_XOR1 0xB1          // quad_perm [1,0,3,2]
#define DPP_XOR2 0x4E          // quad_perm [2,3,0,1]

template<int CTRL>
__device__ __forceinline__ float dppf(float v) {
    return __int_as_float(__builtin_amdgcn_update_dpp(
        0, __float_as_int(v), CTRL, 0xF, 0xF, true));
}
template<int CTRL>
__device__ __forceinline__ int dppi(int v) {
    return __builtin_amdgcn_update_dpp(0, v, CTRL, 0xF, 0xF, true);
}

__global__ __launch_bounds__(256, 6)
void pq_head_kernel(const float* __restrict__ x,
                    const float* __restrict__ cb,
                    float* __restrict__ out) {
    __shared__ float xs[2][STGF];   // 24 KiB double buffer

    const int t     = threadIdx.x;
    const int kq    = t & 3;        // k-quarter (lane within quad)
    const int mloc  = t >> 2;       // 0..63
    const int mhalf = blockIdx.y;   // 0/1
    const int m     = mhalf * 64 + mloc;
    const int b0    = blockIdx.x * BROWS;

    // Load this lane's 8 codebook rows (48 floats, 192-B aligned) and pack
    // code-pairs into v2f: cpk[p][e] = (cb[2p][e], cb[2p+1][e]).
    v2f cpk[4][D_SUB];
    {
        float cc[48];
        const float4* cb4 = reinterpret_cast<const float4*>(
            cb + ((size_t)m * K_CB + (size_t)kq * 8) * D_SUB);
        #pragma unroll
        for (int i = 0; i < 12; ++i) {
            float4 v = cb4[i];
            cc[4*i+0]=v.x; cc[4*i+1]=v.y; cc[4*i+2]=v.z; cc[4*i+3]=v.w;
        }
        #pragma unroll
        for (int p = 0; p < 4; ++p)
            #pragma unroll
            for (int e = 0; e < D_SUB; ++e)
                cpk[p][e] = (v2f){cc[(2*p)*D_SUB + e], cc[(2*p+1)*D_SUB + e]};
    }

    const float* xh = x   + (size_t)mhalf * HALFF;  // half-row base
    float*       oh = out + (size_t)mhalf * HALFF;

    // Stage-invariant (row, col) for the coalesced stage load.
    int pr[3], pc[3];
    #pragma unroll
    for (int i = 0; i < 3; ++i) {
        int f = (i * 256 + t) * 4;          // float index within stage (<3072)
        pr[i] = f / HALFF;
        pc[i] = f - pr[i] * HALFF;
    }

    // Prefetch stage 0 (3 x dwordx4 per thread, fully coalesced).
    float4 pf[3];
    #pragma unroll
    for (int i = 0; i < 3; ++i)
        pf[i] = *reinterpret_cast<const float4*>(xh + (size_t)(b0 + pr[i]) * DIM + pc[i]);

    for (int s = 0; s < NSTG; ++s) {
        float* buf = xs[s & 1];
        #pragma unroll
        for (int i = 0; i < 3; ++i)
            *reinterpret_cast<float4*>(&buf[(i * 256 + t) * 4]) = pf[i];
        __syncthreads();   // writers of buf done; stage s+1 writes the OTHER buffer

        if (s + 1 < NSTG) {                 // prefetch next stage; consumer is
            int rb = b0 + (s + 1) * RSTG;   // a ds_write past this stage's compute
            #pragma unroll
            for (int i = 0; i < 3; ++i)
                pf[i] = *reinterpret_cast<const float4*>(
                    xh + (size_t)(rb + pr[i]) * DIM + pc[i]);
        }

        // ---- phase A: 8 winner computations -> kg8[] ----
        int kg8[RSTG];
        #pragma unroll
        for (int r = 0; r < RSTG; ++r) {
            const float* xr = &buf[r * HALFF + mloc * D_SUB];  // quad-broadcast
            float2 x01 = *reinterpret_cast<const float2*>(xr);
            float2 x23 = *reinterpret_cast<const float2*>(xr + 2);
            float2 x45 = *reinterpret_cast<const float2*>(xr + 4);
            float xv[6] = {x01.x, x01.y, x23.x, x23.y, x45.x, x45.y};
            v2f xxe[6];
            #pragma unroll
            for (int e = 0; e < 6; ++e) xxe[e] = (v2f){xv[e], xv[e]};

            // 8 packed dots, kept live in acc[4].
            v2f acc[4];
            #pragma unroll
            for (int p = 0; p < 4; ++p) {
                v2f a = cpk[p][0] * xxe[0];
                #pragma unroll
                for (int e = 1; e < 6; ++e)
                    a = __builtin_elementwise_fma(cpk[p][e], xxe[e], a);
                acc[p] = a;
            }

            // Quad max via pk-max tree + 2 DPP merges (pure VALU, ~7 ops).
            v2f t0 = __builtin_elementwise_max(acc[0], acc[1]);
            v2f t1 = __builtin_elementwise_max(acc[2], acc[3]);
            v2f t2 = __builtin_elementwise_max(t0, t1);
            float best1 = fmaxf(t2.x, t2.y);
            best1 = fmaxf(best1, dppf<DPP_XOR1>(best1));
            best1 = fmaxf(best1, dppf<DPP_XOR2>(best1));

            // Epsilon-match mask: bit j set iff dot_j > best1 - 1e-5.
            // (dots ~0.02 scale; 1e-5 >> f32 dot error but << typical gaps.)
            const float thr = best1 - EPS_TIE;
            int msk = 0;
            #pragma unroll
            for (int p = 0; p < 4; ++p) {
                if (acc[p].x > thr) msk |= 1 << (2*p);
                if (acc[p].y > thr) msk |= 1 << (2*p+1);
            }
            int full = msk << (kq * 8);
            full |= dppi<DPP_XOR1>(full);
            full |= dppi<DPP_XOR2>(full);   // quad-uniform 32-bit mask

            int kg;
            if (__builtin_popcount(full) == 1) {
                // Unique near-max => it IS the strict argmax.
                kg = __builtin_ctz(full);
            } else {
                // Ambiguous within 1e-5 (incl. exact ties): exact fp64 argmax,
                // first-wins — matches jnp.argmax. Quad-uniform branch.
                const float* crow = cb + (size_t)m * K_CB * D_SUB;
                double db = -1e300; int dkg = 0;
                for (int k2 = 0; k2 < K_CB; ++k2) {
                    double sa = 0.0;
                    for (int e = 0; e < 6; ++e)
                        sa = fma((double)crow[k2*6+e], (double)xv[e], sa);
                    if (sa > db) { db = sa; dkg = k2; }
                }
                kg = dkg;
            }
            kg8[r] = kg;
        }

        // ---- phase B: 8 independent winner gathers (cb is L1/L2-hot) ----
        const bool act = (kq < 3);
        float2 gv[RSTG];
        if (act) {
            #pragma unroll
            for (int r = 0; r < RSTG; ++r)
                gv[r] = *(reinterpret_cast<const float2*>(
                    cb + ((size_t)m * K_CB + (size_t)kg8[r]) * D_SUB) + kq);
        }

        __builtin_amdgcn_sched_barrier(0);  // keep all gathers above all stores

        // ---- phase C: 8 coalesced float2 stores (48/64 lanes -> full lines) ----
        if (act) {
            #pragma unroll
            for (int r = 0; r < RSTG; ++r) {
                float* dst = oh + (size_t)(b0 + s * RSTG + r) * DIM + mloc * D_SUB;
                *(reinterpret_cast<float2*>(dst) + kq) = gv[r];
            }
        }
    }
}

extern "C" void kernel_launch(void* const* d_in, const int* in_sizes, int n_in,
                              void* d_out, int out_size, void* d_ws, size_t ws_size,
                              hipStream_t stream) {
    const float* x  = (const float*)d_in[0];   // (32768, 768) fp32
    const float* cb = (const float*)d_in[1];   // (128, 32, 6) fp32
    float* out = (float*)d_out;                // (32768, 768) fp32

    dim3 grid(BATCH / BROWS, 2);   // 2048 x 2 = 4096 blocks
    dim3 block(256);               // 64 m x 4 k-quarters
    hipLaunchKernelGGL(pq_head_kernel, grid, block, 0, stream, x, cb, out);
}

// Round 4
// 219.662 us; speedup vs baseline: 1.6399x; 1.6399x over previous
//
#include <hip/hip_runtime.h>
#include <float.h>

// PQHead forward: out[b, m*6+d] = codebooks[m, argmax_k dot(x[b,m,:], cb[m,k,:]), d]
// (straight-through estimator: forward value of quant is exactly `discrete`)
//
// R10: R9's select diet at R6's proven schedule.
//  - R9 post-mortem: __launch_bounds__(256,6) forced VGPR budget ~42 ->
//    VGPR_Count 40 -> scratch spills -> WRITE 427 MB / FETCH 200 MB, 244us.
//    The select diet itself was correct (absmax 0.0). Revert to (256,4).
//  - R8 standing fact: co-residency breadth >1024 blocks thrashes L3
//    (x+out ~192 MB vs 256 MB). Do NOT raise occupancy on this kernel.
//  - Select: pk-max tree + DPP quad-max (~8 ops) + epsilon-match mask
//    (~25 ops) replaces running top-2 (~64 ops). popcount==1 -> ctz is the
//    exact argmax; else quad-uniform fp64 exact fallback (same trigger
//    condition as R6: runner-up within 1e-5 of best).

typedef float v2f __attribute__((ext_vector_type(2)));

#define BATCH 32768
#define DIM   768
#define K_CB  32
#define D_SUB 6
#define BROWS 16               // rows per block
#define RSTG  8                // rows per LDS stage
#define NSTG  (BROWS/RSTG)     // 2 stages
#define HALFF 384              // floats per half row (64 m * 6)
#define STGF  (RSTG*HALFF)     // 3072 floats = 12 KiB per buffer
#define EPS_TIE 1e-5f

#define DPP_XOR1 0xB1          // quad_perm [1,0,3,2]
#define DPP_XOR2 0x4E          // quad_perm [2,3,0,1]

template<int CTRL>
__device__ __forceinline__ float dppf(float v) {
    return __int_as_float(__builtin_amdgcn_update_dpp(
        0, __float_as_int(v), CTRL, 0xF, 0xF, true));
}
template<int CTRL>
__device__ __forceinline__ int dppi(int v) {
    return __builtin_amdgcn_update_dpp(0, v, CTRL, 0xF, 0xF, true);
}

__global__ __launch_bounds__(256, 4)
void pq_head_kernel(const float* __restrict__ x,
                    const float* __restrict__ cb,
                    float* __restrict__ out) {
    __shared__ float xs[2][STGF];   // 24 KiB double buffer

    const int t     = threadIdx.x;
    const int kq    = t & 3;        // k-quarter (lane within quad)
    const int mloc  = t >> 2;       // 0..63
    const int mhalf = blockIdx.y;   // 0/1
    const int m     = mhalf * 64 + mloc;
    const int b0    = blockIdx.x * BROWS;

    // Load this lane's 8 codebook rows (48 floats, 192-B aligned) and pack
    // code-pairs into v2f: cpk[p][e] = (cb[2p][e], cb[2p+1][e]).
    v2f cpk[4][D_SUB];
    {
        float cc[48];
        const float4* cb4 = reinterpret_cast<const float4*>(
            cb + ((size_t)m * K_CB + (size_t)kq * 8) * D_SUB);
        #pragma unroll
        for (int i = 0; i < 12; ++i) {
            float4 v = cb4[i];
            cc[4*i+0]=v.x; cc[4*i+1]=v.y; cc[4*i+2]=v.z; cc[4*i+3]=v.w;
        }
        #pragma unroll
        for (int p = 0; p < 4; ++p)
            #pragma unroll
            for (int e = 0; e < D_SUB; ++e)
                cpk[p][e] = (v2f){cc[(2*p)*D_SUB + e], cc[(2*p+1)*D_SUB + e]};
    }

    const float* xh = x   + (size_t)mhalf * HALFF;  // half-row base
    float*       oh = out + (size_t)mhalf * HALFF;

    // Stage-invariant (row, col) for the coalesced stage load.
    int pr[3], pc[3];
    #pragma unroll
    for (int i = 0; i < 3; ++i) {
        int f = (i * 256 + t) * 4;          // float index within stage (<3072)
        pr[i] = f / HALFF;
        pc[i] = f - pr[i] * HALFF;
    }

    // Prefetch stage 0 (3 x dwordx4 per thread, fully coalesced).
    float4 pf[3];
    #pragma unroll
    for (int i = 0; i < 3; ++i)
        pf[i] = *reinterpret_cast<const float4*>(xh + (size_t)(b0 + pr[i]) * DIM + pc[i]);

    for (int s = 0; s < NSTG; ++s) {
        float* buf = xs[s & 1];
        #pragma unroll
        for (int i = 0; i < 3; ++i)
            *reinterpret_cast<float4*>(&buf[(i * 256 + t) * 4]) = pf[i];
        __syncthreads();   // writers of buf done; stage s+1 writes the OTHER buffer

        if (s + 1 < NSTG) {                 // prefetch next stage; consumer is
            int rb = b0 + (s + 1) * RSTG;   // a ds_write past this stage's compute
            #pragma unroll
            for (int i = 0; i < 3; ++i)
                pf[i] = *reinterpret_cast<const float4*>(
                    xh + (size_t)(rb + pr[i]) * DIM + pc[i]);
        }

        // ---- phase A: 8 winner computations -> kg8[] ----
        int kg8[RSTG];
        #pragma unroll
        for (int r = 0; r < RSTG; ++r) {
            const float* xr = &buf[r * HALFF + mloc * D_SUB];  // quad-broadcast
            float2 x01 = *reinterpret_cast<const float2*>(xr);
            float2 x23 = *reinterpret_cast<const float2*>(xr + 2);
            float2 x45 = *reinterpret_cast<const float2*>(xr + 4);
            float xv[6] = {x01.x, x01.y, x23.x, x23.y, x45.x, x45.y};
            v2f xxe[6];
            #pragma unroll
            for (int e = 0; e < 6; ++e) xxe[e] = (v2f){xv[e], xv[e]};

            // 8 packed dots, kept live in acc[4].
            v2f acc[4];
            #pragma unroll
            for (int p = 0; p < 4; ++p) {
                v2f a = cpk[p][0] * xxe[0];
                #pragma unroll
                for (int e = 1; e < 6; ++e)
                    a = __builtin_elementwise_fma(cpk[p][e], xxe[e], a);
                acc[p] = a;
            }

            // Quad max via pk-max tree + 2 DPP merges (pure VALU, ~8 ops).
            v2f t0 = __builtin_elementwise_max(acc[0], acc[1]);
            v2f t1 = __builtin_elementwise_max(acc[2], acc[3]);
            v2f t2 = __builtin_elementwise_max(t0, t1);
            float best1 = fmaxf(t2.x, t2.y);
            best1 = fmaxf(best1, dppf<DPP_XOR1>(best1));
            best1 = fmaxf(best1, dppf<DPP_XOR2>(best1));

            // Epsilon-match mask: bit j set iff dot_j > best1 - 1e-5.
            // (dots ~0.02 scale; 1e-5 >> f32 dot error but << typical gaps.)
            const float thr = best1 - EPS_TIE;
            int msk = 0;
            #pragma unroll
            for (int p = 0; p < 4; ++p) {
                if (acc[p].x > thr) msk |= 1 << (2*p);
                if (acc[p].y > thr) msk |= 1 << (2*p+1);
            }
            int full = msk << (kq * 8);
            full |= dppi<DPP_XOR1>(full);
            full |= dppi<DPP_XOR2>(full);   // quad-uniform 32-bit mask

            int kg;
            if (__builtin_popcount(full) == 1) {
                // Unique near-max => it IS the strict argmax.
                kg = __builtin_ctz(full);
            } else {
                // Ambiguous within 1e-5 (incl. exact ties): exact fp64 argmax,
                // first-wins — matches jnp.argmax. Quad-uniform branch.
                const float* crow = cb + (size_t)m * K_CB * D_SUB;
                double db = -1e300; int dkg = 0;
                for (int k2 = 0; k2 < K_CB; ++k2) {
                    double sa = 0.0;
                    for (int e = 0; e < 6; ++e)
                        sa = fma((double)crow[k2*6+e], (double)xv[e], sa);
                    if (sa > db) { db = sa; dkg = k2; }
                }
                kg = dkg;
            }
            kg8[r] = kg;
        }

        // ---- phase B: 8 independent winner gathers (cb is L1/L2-hot) ----
        const bool act = (kq < 3);
        float2 gv[RSTG];
        if (act) {
            #pragma unroll
            for (int r = 0; r < RSTG; ++r)
                gv[r] = *(reinterpret_cast<const float2*>(
                    cb + ((size_t)m * K_CB + (size_t)kg8[r]) * D_SUB) + kq);
        }

        __builtin_amdgcn_sched_barrier(0);  // keep all gathers above all stores

        // ---- phase C: 8 coalesced float2 stores (48/64 lanes -> full lines) ----
        if (act) {
            #pragma unroll
            for (int r = 0; r < RSTG; ++r) {
                float* dst = oh + (size_t)(b0 + s * RSTG + r) * DIM + mloc * D_SUB;
                *(reinterpret_cast<float2*>(dst) + kq) = gv[r];
            }
        }
    }
}

extern "C" void kernel_launch(void* const* d_in, const int* in_sizes, int n_in,
                              void* d_out, int out_size, void* d_ws, size_t ws_size,
                              hipStream_t stream) {
    const float* x  = (const float*)d_in[0];   // (32768, 768) fp32
    const float* cb = (const float*)d_in[1];   // (128, 32, 6) fp32
    float* out = (float*)d_out;                // (32768, 768) fp32

    dim3 grid(BATCH / BROWS, 2);   // 2048 x 2 = 4096 blocks
    dim3 block(256);               // 64 m x 4 k-quarters
    hipLaunchKernelGGL(pq_head_kernel, grid, block, 0, stream, x, cb, out);
}